// Round 6
// baseline (311.815 us; speedup 1.0000x reference)
//
#include <hip/hip_runtime.h>

// GraphTransformerBlock2: GATConv(H=3,C=64, edge_dim=5, self-loops w/ mean fill)
// -> linear1 -> LN(x + .) -> linear2 -> LN(lin + .)
// All float32 I/O. edge_index int32 (2,E): src=ei[0:E], dst=ei[E:2E].
//
// R5: k_gat VALU diet:
//  - xsp packed gather table: [n][lane] = uint2{bf(h0)|bf(h1), bf(h2)} ->
//    phase B = 1 dwordx2 + 3 unpack + 3 fma per edge (was 3 loads + 3 addr).
//  - ae-segment-sum moved to 3 f32 atomics in k_fill (exact, linear) ->
//    payload 8B/edge, phase A sheds ae handling, per-node reduces 6 -> 3.
//  - log2e folded into we/a_src/a_dst at prep -> exp2f (native v_exp_f32).
//  - phase B 2x unroll with split accumulator chains.

#define HH 3
#define CC 64
#define DIN 64
#define ED 5
#define HC 192
#define NEG_SLOPE 0.2f
#define LN_EPS 1e-5f
#define LOG2E 1.44269504f

typedef __attribute__((ext_vector_type(8))) short bf16x8;
typedef __attribute__((ext_vector_type(4))) float f32x4;

__device__ __forceinline__ float leaky(float l) { return (l >= 0.f) ? l : NEG_SLOPE * l; }

__device__ __forceinline__ unsigned short f2bf(float f) {
    unsigned u = __float_as_uint(f);
    unsigned r = (u + 0x7FFFu + ((u >> 16) & 1u)) >> 16;   // RNE
    return (unsigned short)r;
}
__device__ __forceinline__ float bf_lo(unsigned v) {       // low 16 bits as bf16
    return __uint_as_float(v << 16);
}
__device__ __forceinline__ float bf_hi(unsigned v) {       // high 16 bits as bf16
    return __uint_as_float(v & 0xFFFF0000u);
}

__device__ __forceinline__ bf16x8 pack8(float4 a, float4 b) {
    bf16x8 r;
    r[0] = (short)f2bf(a.x); r[1] = (short)f2bf(a.y);
    r[2] = (short)f2bf(a.z); r[3] = (short)f2bf(a.w);
    r[4] = (short)f2bf(b.x); r[5] = (short)f2bf(b.y);
    r[6] = (short)f2bf(b.z); r[7] = (short)f2bf(b.w);
    return r;
}

// ---------- prep (bf16 transposed weights + folded bias + we*log2e) + cnt ----------
#define PREP_TOT (HC*DIN + DIN*HC + CC*CC + CC + ED*HH)
#define PREP_BLOCKS 30
__global__ __launch_bounds__(256) void k_prep_cnt(const float* __restrict__ lin_w,
                                                  const float* __restrict__ w1,
                                                  const float* __restrict__ w2,
                                                  const float* __restrict__ b1,
                                                  const float* __restrict__ gat_bias,
                                                  const float* __restrict__ lin_edge_w,
                                                  const float* __restrict__ att_edge,
                                                  unsigned short* __restrict__ linwt,
                                                  unsigned short* __restrict__ w1t,
                                                  unsigned short* __restrict__ w2t,
                                                  float* __restrict__ b1p,
                                                  float* __restrict__ we,
                                                  const int* __restrict__ ei,
                                                  int* __restrict__ icnt, int E) {
    if (blockIdx.x < PREP_BLOCKS) {
        for (int i = blockIdx.x * 256 + threadIdx.x; i < PREP_TOT; i += PREP_BLOCKS * 256) {
            if (i < HC * DIN) {
                int c = i >> 6, k = i & 63;
                linwt[i] = f2bf(lin_w[k * HC + c]);
            } else if (i < 2 * HC * DIN) {
                int j = i - HC * DIN;
                int c = j / HC, k = j - c * HC;
                w1t[j] = f2bf(w1[k * CC + c]);
            } else if (i < 2 * HC * DIN + CC * CC) {
                int j = i - 2 * HC * DIN;
                int c = j >> 6, k = j & 63;
                w2t[j] = f2bf(w2[k * CC + c]);
            } else if (i < 2 * HC * DIN + CC * CC + CC) {
                int c = i - (2 * HC * DIN + CC * CC);
                float s = b1[c];
                for (int k = 0; k < HC; ++k) s += gat_bias[k] * w1[k * CC + c];
                b1p[c] = s;
            } else {
                int q = i - (2 * HC * DIN + CC * CC + CC);
                int d = q / HH, h = q - d * HH;
                float s = 0.f;
                for (int c = 0; c < CC; ++c)
                    s += lin_edge_w[d * HC + h * CC + c] * att_edge[h * CC + c];
                we[q] = s * LOG2E;                     // pre-scale for exp2
            }
        }
    } else {
        int nb = gridDim.x - PREP_BLOCKS;
        for (int e = (blockIdx.x - PREP_BLOCKS) * 256 + threadIdx.x; e < E; e += nb * 256)
            atomicAdd(&icnt[ei[E + e]], 1);
    }
}

// ---------- xs = x @ lin_w (MFMA) -> packed xsp + a_src/a_dst (pre-scaled) ----------
__global__ __launch_bounds__(256) void k_xs(const float* __restrict__ x,
                                            const unsigned short* __restrict__ linwt,
                                            const float* __restrict__ att_src,
                                            const float* __restrict__ att_dst,
                                            uint2* __restrict__ xsp,
                                            float* __restrict__ a_src,
                                            float* __restrict__ a_dst, int N) {
    int lane = threadIdx.x & 63, w = threadIdx.x >> 6;
    int l15 = lane & 15, kg = (lane >> 4) * 8;
    int nb = blockIdx.x * 64;
    int arow = nb + w * 16 + l15;
    int arow_c = min(arow, N - 1);

    f32x4 acc[12];
    #pragma unroll
    for (int ct = 0; ct < 12; ++ct) acc[ct] = (f32x4){0.f, 0.f, 0.f, 0.f};

    #pragma unroll
    for (int k0 = 0; k0 < DIN; k0 += 32) {
        const float* ap = x + (size_t)arow_c * DIN + k0 + kg;
        float4 a0 = *(const float4*)ap;
        float4 a1 = *(const float4*)(ap + 4);
        bf16x8 af = pack8(a0, a1);
        #pragma unroll
        for (int ct = 0; ct < 12; ++ct) {
            bf16x8 bf = *(const bf16x8*)(linwt + (size_t)(ct * 16 + l15) * DIN + k0 + kg);
            acc[ct] = __builtin_amdgcn_mfma_f32_16x16x32_bf16(af, bf, acc[ct], 0, 0, 0);
        }
    }

    float asv[12], adv[12];
    #pragma unroll
    for (int ct = 0; ct < 12; ++ct) {
        int c = ct * 16 + l15;
        asv[ct] = att_src[c]; adv[ct] = att_dst[c];
    }

    int rbase = nb + w * 16 + (lane >> 4) * 4;
    #pragma unroll
    for (int j = 0; j < 4; ++j) {
        int r = rbase + j;
        bool ok = r < N;
        float ps0 = 0.f, ps1 = 0.f, ps2 = 0.f, pd0 = 0.f, pd1 = 0.f, pd2 = 0.f;
        #pragma unroll
        for (int ct = 0; ct < 12; ++ct) {
            float v = acc[ct][j];
            float s = v * asv[ct], d = v * adv[ct];
            if (ct < 4)      { ps0 += s; pd0 += d; }
            else if (ct < 8) { ps1 += s; pd1 += d; }
            else             { ps2 += s; pd2 += d; }
        }
        if (ok) {
            #pragma unroll
            for (int ct = 0; ct < 4; ++ct) {
                uint2 pk;
                pk.x = (unsigned)f2bf(acc[ct][j]) | ((unsigned)f2bf(acc[ct + 4][j]) << 16);
                pk.y = (unsigned)f2bf(acc[ct + 8][j]);
                xsp[(size_t)r * CC + ct * 16 + l15] = pk;
            }
        }
        #pragma unroll
        for (int o = 1; o < 16; o <<= 1) {
            ps0 += __shfl_xor(ps0, o, 64); pd0 += __shfl_xor(pd0, o, 64);
            ps1 += __shfl_xor(ps1, o, 64); pd1 += __shfl_xor(pd1, o, 64);
            ps2 += __shfl_xor(ps2, o, 64); pd2 += __shfl_xor(pd2, o, 64);
        }
        if (ok && l15 == 0) {
            a_src[r * HH + 0] = ps0 * LOG2E; a_src[r * HH + 1] = ps1 * LOG2E;
            a_src[r * HH + 2] = ps2 * LOG2E;
            a_dst[r * HH + 0] = pd0 * LOG2E; a_dst[r * HH + 1] = pd1 * LOG2E;
            a_dst[r * HH + 2] = pd2 * LOG2E;
        }
    }
}

// ---------- multi-block exclusive scan (3 kernels) ----------
__global__ __launch_bounds__(256) void k_scan1(const int* __restrict__ icnt,
                                               int* __restrict__ bsum, int N) {
    int i = blockIdx.x * 256 + threadIdx.x;
    int lane = threadIdx.x & 63, wid = threadIdx.x >> 6;
    int v = (i < N) ? icnt[i] : 0;
    #pragma unroll
    for (int o = 32; o; o >>= 1) v += __shfl_xor(v, o, 64);
    __shared__ int wt[4];
    if (lane == 0) wt[wid] = v;
    __syncthreads();
    if (threadIdx.x == 0) bsum[blockIdx.x] = wt[0] + wt[1] + wt[2] + wt[3];
}

__global__ __launch_bounds__(1024) void k_scan2(const int* __restrict__ bsum,
                                                int* __restrict__ boff, int nb) {
    __shared__ int s[1024];
    int t = threadIdx.x;
    int v = (t < nb) ? bsum[t] : 0;
    s[t] = v;
    __syncthreads();
    for (int d = 1; d < 1024; d <<= 1) {
        int u = (t >= d) ? s[t - d] : 0;
        __syncthreads();
        s[t] += u;
        __syncthreads();
    }
    if (t < nb) boff[t] = s[t] - v;   // exclusive
}

__global__ __launch_bounds__(256) void k_scan3(const int* __restrict__ icnt,
                                               const int* __restrict__ boff,
                                               int* __restrict__ off,
                                               int* __restrict__ cursor, int N) {
    int i = blockIdx.x * 256 + threadIdx.x;
    int lane = threadIdx.x & 63, wid = threadIdx.x >> 6;
    int v = (i < N) ? icnt[i] : 0;
    int incl = v;
    #pragma unroll
    for (int o = 1; o < 64; o <<= 1) {
        int u = __shfl_up(incl, o, 64);
        if (lane >= o) incl += u;
    }
    __shared__ int wt[4];
    if (lane == 63) wt[wid] = incl;
    __syncthreads();
    int wpre = 0;
    for (int w = 0; w < wid; ++w) wpre += wt[w];
    int excl = boff[blockIdx.x] + wpre + incl - v;
    if (i < N) {
        off[i] = excl;
        cursor[i] = excl;
        if (i == N - 1) off[N] = excl + v;
    }
}

// ---------- payload fill (CSR order), 8B/edge + ae segment-sum atomics ----------
// pk = { bf(lp0)|bf(lp1)<<16, bf(lp2)|(src<<16) }   (src<65536; else srcext)
__global__ __launch_bounds__(256) void k_fill(const float* __restrict__ ea,
                                              const int* __restrict__ ei,
                                              const float* __restrict__ a_src,
                                              const float* __restrict__ we,
                                              int* __restrict__ cursor,
                                              uint2* __restrict__ payload,
                                              int* __restrict__ srcext,
                                              float* __restrict__ aesum,
                                              int E, int use_ext) {
    int e = blockIdx.x * blockDim.x + threadIdx.x;
    if (e >= E) return;
    int s = ei[e], d = ei[E + e];
    float attr[ED];
    #pragma unroll
    for (int j = 0; j < ED; ++j) attr[j] = ea[(size_t)e * ED + j];
    float aeh[HH], lp[HH];
    #pragma unroll
    for (int h = 0; h < HH; ++h) {
        float a = 0.f;
        #pragma unroll
        for (int j = 0; j < ED; ++j) a += attr[j] * we[j * HH + h];   // we pre-scaled
        aeh[h] = a;
        lp[h] = a_src[s * HH + h] + a;                                 // both scaled
    }
    atomicAdd(&aesum[d * HH + 0], aeh[0]);
    atomicAdd(&aesum[d * HH + 1], aeh[1]);
    atomicAdd(&aesum[d * HH + 2], aeh[2]);
    int pos = atomicAdd(&cursor[d], 1);
    uint2 pk;
    pk.x = (unsigned)f2bf(lp[0]) | ((unsigned)f2bf(lp[1]) << 16);
    pk.y = (unsigned)f2bf(lp[2]) | ((unsigned)s << 16);
    payload[pos] = pk;
    if (use_ext) srcext[pos] = s;
}

// ---------- per-dst softmax + gather: two-phase, packed ----------
__global__ __launch_bounds__(256) void k_gat(const uint2* __restrict__ xsp,
                                             const float* __restrict__ a_src,
                                             const float* __restrict__ a_dst,
                                             const float* __restrict__ aesum,
                                             const int* __restrict__ off,
                                             const uint2* __restrict__ payload,
                                             const int* __restrict__ srcext,
                                             unsigned short* __restrict__ oaccb,
                                             int N, int use_ext) {
    __shared__ float4 wbuf[4][64];
    int lane = threadIdx.x & 63;
    int wid  = threadIdx.x >> 6;
    for (int n = blockIdx.x * 4 + wid; n < N; n += gridDim.x * 4) {
        int beg = off[n], end = off[n + 1];
        int deg = end - beg;
        float ad0 = a_dst[n * HH + 0], ad1 = a_dst[n * HH + 1], ad2 = a_dst[n * HH + 2];
        float pden0 = 0.f, pden1 = 0.f, pden2 = 0.f;
        float a0A = 0.f, a1A = 0.f, a2A = 0.f;
        float a0B = 0.f, a1B = 0.f, a2B = 0.f;

        for (int c0 = 0; c0 < deg; c0 += 64) {
            int cn = min(deg - c0, 64);
            // --- phase A: lane = edge ---
            float w0 = 0.f, w1 = 0.f, w2 = 0.f;
            int src = 0;
            if (lane < cn) {
                uint2 p = payload[beg + c0 + lane];
                w0 = exp2f(leaky(bf_lo(p.x) + ad0));
                w1 = exp2f(leaky(bf_hi(p.x) + ad1));
                w2 = exp2f(leaky(bf_lo(p.y) + ad2));
                src = (int)(p.y >> 16);
                if (use_ext) src = srcext[beg + c0 + lane];
                pden0 += w0; pden1 += w1; pden2 += w2;
            }
            wbuf[wid][lane] = make_float4(w0, w1, w2, __int_as_float(src));
            // --- phase B: lane = feature, one dwordx2 gather per edge ---
            int i = 0;
            for (; i + 2 <= cn; i += 2) {
                float4 ta = wbuf[wid][i];
                float4 tb = wbuf[wid][i + 1];
                unsigned ia = (unsigned)__float_as_int(ta.w) * CC + lane;
                unsigned ib = (unsigned)__float_as_int(tb.w) * CC + lane;
                uint2 va = xsp[ia];
                uint2 vb = xsp[ib];
                a0A += ta.x * bf_lo(va.x); a1A += ta.y * bf_hi(va.x); a2A += ta.z * bf_lo(va.y);
                a0B += tb.x * bf_lo(vb.x); a1B += tb.y * bf_hi(vb.x); a2B += tb.z * bf_lo(vb.y);
            }
            if (i < cn) {
                float4 ta = wbuf[wid][i];
                unsigned ia = (unsigned)__float_as_int(ta.w) * CC + lane;
                uint2 va = xsp[ia];
                a0A += ta.x * bf_lo(va.x); a1A += ta.y * bf_hi(va.x); a2A += ta.z * bf_lo(va.y);
            }
        }

        // reduce per-lane den partials
        #pragma unroll
        for (int o = 32; o; o >>= 1) {
            pden0 += __shfl_xor(pden0, o, 64);
            pden1 += __shfl_xor(pden1, o, 64);
            pden2 += __shfl_xor(pden2, o, 64);
        }

        // self loop (edge attr = mean of incoming, 0 if deg==0); all pre-scaled
        float dc = fmaxf((float)deg, 1.0f);
        float inv_dc = 1.0f / dc;
        float sl0 = leaky(a_src[n * HH + 0] + ad0 + aesum[n * HH + 0] * inv_dc);
        float sl1 = leaky(a_src[n * HH + 1] + ad1 + aesum[n * HH + 1] * inv_dc);
        float sl2 = leaky(a_src[n * HH + 2] + ad2 + aesum[n * HH + 2] * inv_dc);
        float e0 = exp2f(sl0), e1 = exp2f(sl1), e2 = exp2f(sl2);
        uint2 vn = xsp[(unsigned)n * CC + lane];
        float den0 = pden0 + e0, den1 = pden1 + e1, den2 = pden2 + e2;
        float acc0 = a0A + a0B + e0 * bf_lo(vn.x);
        float acc1 = a1A + a1B + e1 * bf_hi(vn.x);
        float acc2 = a2A + a2B + e2 * bf_lo(vn.y);
        size_t nbse = (size_t)n * HC;
        oaccb[nbse + 0 * CC + lane] = f2bf(acc0 / den0);
        oaccb[nbse + 1 * CC + lane] = f2bf(acc1 / den1);
        oaccb[nbse + 2 * CC + lane] = f2bf(acc2 / den2);
    }
}

// ---------- fused MLP: GEMM1 -> LN1 -> GEMM2 -> LN2 (MFMA, in-reg LN) ----------
__global__ __launch_bounds__(256) void k_mlp(const unsigned short* __restrict__ oaccb,
                                             const unsigned short* __restrict__ w1t,
                                             const unsigned short* __restrict__ w2t,
                                             const float* __restrict__ b1p,
                                             const float* __restrict__ x,
                                             const float* __restrict__ g1,
                                             const float* __restrict__ be1,
                                             const float* __restrict__ b2,
                                             const float* __restrict__ g2,
                                             const float* __restrict__ be2,
                                             float* __restrict__ out, int N) {
    __shared__ unsigned short H1[64 * 72];   // [node-in-tile][feature] bf16, pad 72
    int lane = threadIdx.x & 63, w = threadIdx.x >> 6;
    int l15 = lane & 15, kg = (lane >> 4) * 8;
    int nb = blockIdx.x * 64;
    int arow = nb + w * 16 + l15;
    int arow_c = min(arow, N - 1);

    float c_b1[4], c_g1[4], c_be1[4], c_b2[4], c_g2[4], c_be2[4];
    #pragma unroll
    for (int ct = 0; ct < 4; ++ct) {
        int c = ct * 16 + l15;
        c_b1[ct] = b1p[c]; c_g1[ct] = g1[c]; c_be1[ct] = be1[c];
        c_b2[ct] = b2[c];  c_g2[ct] = g2[c]; c_be2[ct] = be2[c];
    }

    // GEMM1: [64 x 192] @ [192 x 64], A read directly as bf16
    f32x4 acc[4];
    #pragma unroll
    for (int ct = 0; ct < 4; ++ct) acc[ct] = (f32x4){0.f, 0.f, 0.f, 0.f};
    #pragma unroll
    for (int k0 = 0; k0 < HC; k0 += 32) {
        bf16x8 af = *(const bf16x8*)(oaccb + (size_t)arow_c * HC + k0 + kg);
        #pragma unroll
        for (int ct = 0; ct < 4; ++ct) {
            bf16x8 bf = *(const bf16x8*)(w1t + (size_t)(ct * 16 + l15) * HC + k0 + kg);
            acc[ct] = __builtin_amdgcn_mfma_f32_16x16x32_bf16(af, bf, acc[ct], 0, 0, 0);
        }
    }

    // epilogue1: y = acc + b1' + x ; LN1 -> h1 (regs + LDS bf16)
    int rbase = nb + w * 16 + (lane >> 4) * 4;
    int rloc0 = w * 16 + (lane >> 4) * 4;
    float h1v[4][4];
    float y[4][4];
    #pragma unroll
    for (int j = 0; j < 4; ++j) {
        int r = min(rbase + j, N - 1);
        #pragma unroll
        for (int ct = 0; ct < 4; ++ct)
            y[ct][j] = acc[ct][j] + c_b1[ct] + x[(size_t)r * DIN + ct * 16 + l15];
    }
    #pragma unroll
    for (int j = 0; j < 4; ++j) {
        float s = y[0][j] + y[1][j] + y[2][j] + y[3][j];
        #pragma unroll
        for (int o = 1; o < 16; o <<= 1) s += __shfl_xor(s, o, 64);
        float m = s * (1.0f / CC);
        float vs = 0.f;
        #pragma unroll
        for (int ct = 0; ct < 4; ++ct) { float d = y[ct][j] - m; vs += d * d; }
        #pragma unroll
        for (int o = 1; o < 16; o <<= 1) vs += __shfl_xor(vs, o, 64);
        float inv = rsqrtf(vs * (1.0f / CC) + LN_EPS);
        #pragma unroll
        for (int ct = 0; ct < 4; ++ct) {
            float h = (y[ct][j] - m) * inv * c_g1[ct] + c_be1[ct];
            h1v[ct][j] = h;
            H1[(rloc0 + j) * 72 + ct * 16 + l15] = f2bf(h);
        }
    }
    __syncthreads();

    // GEMM2: [64 x 64] @ [64 x 64]
    f32x4 acc2[4];
    #pragma unroll
    for (int ct = 0; ct < 4; ++ct) acc2[ct] = (f32x4){0.f, 0.f, 0.f, 0.f};
    #pragma unroll
    for (int k0 = 0; k0 < CC; k0 += 32) {
        bf16x8 af = *(const bf16x8*)&H1[(w * 16 + l15) * 72 + k0 + kg];
        #pragma unroll
        for (int ct = 0; ct < 4; ++ct) {
            bf16x8 bf = *(const bf16x8*)(w2t + (size_t)(ct * 16 + l15) * CC + k0 + kg);
            acc2[ct] = __builtin_amdgcn_mfma_f32_16x16x32_bf16(af, bf, acc2[ct], 0, 0, 0);
        }
    }

    // epilogue2: z = acc2 + b2 + h1 ; LN2 -> out
    #pragma unroll
    for (int j = 0; j < 4; ++j) {
        float z0 = acc2[0][j] + c_b2[0] + h1v[0][j];
        float z1 = acc2[1][j] + c_b2[1] + h1v[1][j];
        float z2 = acc2[2][j] + c_b2[2] + h1v[2][j];
        float z3 = acc2[3][j] + c_b2[3] + h1v[3][j];
        float s = z0 + z1 + z2 + z3;
        #pragma unroll
        for (int o = 1; o < 16; o <<= 1) s += __shfl_xor(s, o, 64);
        float m = s * (1.0f / CC);
        float d0 = z0 - m, d1 = z1 - m, d2 = z2 - m, d3 = z3 - m;
        float vs = d0 * d0 + d1 * d1 + d2 * d2 + d3 * d3;
        #pragma unroll
        for (int o = 1; o < 16; o <<= 1) vs += __shfl_xor(vs, o, 64);
        float inv = rsqrtf(vs * (1.0f / CC) + LN_EPS);
        int r = rbase + j;
        if (r < N) {
            out[(size_t)r * CC + 0 * 16 + l15] = d0 * inv * c_g2[0] + c_be2[0];
            out[(size_t)r * CC + 1 * 16 + l15] = d1 * inv * c_g2[1] + c_be2[1];
            out[(size_t)r * CC + 2 * 16 + l15] = d2 * inv * c_g2[2] + c_be2[2];
            out[(size_t)r * CC + 3 * 16 + l15] = d3 * inv * c_g2[3] + c_be2[3];
        }
    }
}

extern "C" void kernel_launch(void* const* d_in, const int* in_sizes, int n_in,
                              void* d_out, int out_size, void* d_ws, size_t ws_size,
                              hipStream_t stream) {
    const float* x          = (const float*)d_in[0];
    const float* edge_attr  = (const float*)d_in[1];
    const float* lin_w      = (const float*)d_in[2];
    const float* att_src    = (const float*)d_in[3];
    const float* att_dst    = (const float*)d_in[4];
    const float* lin_edge_w = (const float*)d_in[5];
    const float* att_edge   = (const float*)d_in[6];
    const float* gat_bias   = (const float*)d_in[7];
    const float* w1         = (const float*)d_in[8];
    const float* b1         = (const float*)d_in[9];
    const float* ln1_g      = (const float*)d_in[10];
    const float* ln1_b      = (const float*)d_in[11];
    const float* w2         = (const float*)d_in[12];
    const float* b2         = (const float*)d_in[13];
    const float* ln2_g      = (const float*)d_in[14];
    const float* ln2_b      = (const float*)d_in[15];
    const int*   ei         = (const int*)d_in[16];
    float* out = (float*)d_out;

    const int N = in_sizes[0] / DIN;
    const int E = in_sizes[1] / ED;
    const int nb_scan = (N + 255) / 256;
    const int use_ext = (N > 65536) ? 1 : 0;

    char* ws = (char*)d_ws;
    size_t off_b = 0;
    auto alloc = [&](size_t bytes) {
        size_t o = off_b;
        off_b = (off_b + bytes + 255) & ~(size_t)255;
        return o;
    };
    // zeroed region first (single memset)
    int*   icnt  = (int*)(ws + alloc((size_t)N * 4));
    float* aesum = (float*)(ws + alloc((size_t)N * HH * 4));
    size_t zero_bytes = off_b;
    // fully-overwritten region
    uint2* xsp            = (uint2*)(ws + alloc((size_t)N * CC * 8));
    unsigned short* oaccb = (unsigned short*)(ws + alloc((size_t)N * HC * 2));
    float*  a_srcb  = (float*)(ws + alloc((size_t)N * HH * 4));
    float*  a_dstb  = (float*)(ws + alloc((size_t)N * HH * 4));
    int*    offb    = (int*)(ws + alloc((size_t)(N + 1) * 4));
    int*    cursor  = (int*)(ws + alloc((size_t)N * 4));
    int*    bsum    = (int*)(ws + alloc((size_t)nb_scan * 4));
    int*    boff    = (int*)(ws + alloc((size_t)nb_scan * 4));
    uint2*  payload = (uint2*)(ws + alloc((size_t)E * 8));
    int*    srcext  = (int*)(ws + alloc((size_t)E * 4));
    unsigned short* linwt = (unsigned short*)(ws + alloc((size_t)HC * DIN * 2));
    unsigned short* w1t   = (unsigned short*)(ws + alloc((size_t)DIN * HC * 2));
    unsigned short* w2t   = (unsigned short*)(ws + alloc((size_t)CC * CC * 2));
    float* b1p = (float*)(ws + alloc((size_t)CC * 4));
    float* we  = (float*)(ws + alloc((size_t)ED * HH * 4));
    (void)ws_size; (void)n_in; (void)out_size;

    hipMemsetAsync(d_ws, 0, zero_bytes, stream);

    k_prep_cnt<<<PREP_BLOCKS + (E + 255) / 256, 256, 0, stream>>>(
        lin_w, w1, w2, b1, gat_bias, lin_edge_w, att_edge,
        linwt, w1t, w2t, b1p, we, ei, icnt, E);
    k_xs<<<(N + 63) / 64, 256, 0, stream>>>(x, linwt, att_src, att_dst, xsp, a_srcb, a_dstb, N);
    k_scan1<<<nb_scan, 256, 0, stream>>>(icnt, bsum, N);
    k_scan2<<<1, 1024, 0, stream>>>(bsum, boff, nb_scan);
    k_scan3<<<nb_scan, 256, 0, stream>>>(icnt, boff, offb, cursor, N);
    k_fill<<<(E + 255) / 256, 256, 0, stream>>>(edge_attr, ei, a_srcb, we, cursor,
                                                payload, srcext, aesum, E, use_ext);
    k_gat<<<(N + 3) / 4, 256, 0, stream>>>(xsp, a_srcb, a_dstb, aesum, offb, payload,
                                           srcext, oaccb, N, use_ext);
    k_mlp<<<(N + 63) / 64, 256, 0, stream>>>(oaccb, w1t, w2t, b1p, x,
                                             ln1_g, ln1_b, b2, ln2_g, ln2_b, out, N);
}

// Round 7
// 203.995 us; speedup vs baseline: 1.5285x; 1.5285x over previous
//
#include <hip/hip_runtime.h>

// GraphTransformerBlock2: GATConv(H=3,C=64, edge_dim=5, self-loops w/ mean fill)
// -> linear1 -> LN(x + .) -> linear2 -> LN(lin + .)
// All float32 I/O. edge_index int32 (2,E): src=ei[0:E], dst=ei[E:2E].
//
// R6: revert R5's aesum atomics (2.4M scattered f32 atomicAdds -> 150MB RMW
//     write-through, k_fill 156us at 0.5% VALU). ae goes back in the 16B/edge
//     payload, summed lane-parallel in k_gat phase A (R4 scheme, 0 atomics).
//     KEEP R5 wins: packed xsp gather (1 dwordx2/edge), exp2 + log2e folding,
//     split accumulator chains.

#define HH 3
#define CC 64
#define DIN 64
#define ED 5
#define HC 192
#define NEG_SLOPE 0.2f
#define LN_EPS 1e-5f
#define LOG2E 1.44269504f

typedef __attribute__((ext_vector_type(8))) short bf16x8;
typedef __attribute__((ext_vector_type(4))) float f32x4;

__device__ __forceinline__ float leaky(float l) { return (l >= 0.f) ? l : NEG_SLOPE * l; }

__device__ __forceinline__ unsigned short f2bf(float f) {
    unsigned u = __float_as_uint(f);
    unsigned r = (u + 0x7FFFu + ((u >> 16) & 1u)) >> 16;   // RNE
    return (unsigned short)r;
}
__device__ __forceinline__ float bf_lo(unsigned v) { return __uint_as_float(v << 16); }
__device__ __forceinline__ float bf_hi(unsigned v) { return __uint_as_float(v & 0xFFFF0000u); }

__device__ __forceinline__ bf16x8 pack8(float4 a, float4 b) {
    bf16x8 r;
    r[0] = (short)f2bf(a.x); r[1] = (short)f2bf(a.y);
    r[2] = (short)f2bf(a.z); r[3] = (short)f2bf(a.w);
    r[4] = (short)f2bf(b.x); r[5] = (short)f2bf(b.y);
    r[6] = (short)f2bf(b.z); r[7] = (short)f2bf(b.w);
    return r;
}

// ---------- prep (bf16 transposed weights + folded bias + we*log2e) + cnt ----------
#define PREP_TOT (HC*DIN + DIN*HC + CC*CC + CC + ED*HH)
#define PREP_BLOCKS 30
__global__ __launch_bounds__(256) void k_prep_cnt(const float* __restrict__ lin_w,
                                                  const float* __restrict__ w1,
                                                  const float* __restrict__ w2,
                                                  const float* __restrict__ b1,
                                                  const float* __restrict__ gat_bias,
                                                  const float* __restrict__ lin_edge_w,
                                                  const float* __restrict__ att_edge,
                                                  unsigned short* __restrict__ linwt,
                                                  unsigned short* __restrict__ w1t,
                                                  unsigned short* __restrict__ w2t,
                                                  float* __restrict__ b1p,
                                                  float* __restrict__ we,
                                                  const int* __restrict__ ei,
                                                  int* __restrict__ icnt, int E) {
    if (blockIdx.x < PREP_BLOCKS) {
        for (int i = blockIdx.x * 256 + threadIdx.x; i < PREP_TOT; i += PREP_BLOCKS * 256) {
            if (i < HC * DIN) {
                int c = i >> 6, k = i & 63;
                linwt[i] = f2bf(lin_w[k * HC + c]);
            } else if (i < 2 * HC * DIN) {
                int j = i - HC * DIN;
                int c = j / HC, k = j - c * HC;
                w1t[j] = f2bf(w1[k * CC + c]);
            } else if (i < 2 * HC * DIN + CC * CC) {
                int j = i - 2 * HC * DIN;
                int c = j >> 6, k = j & 63;
                w2t[j] = f2bf(w2[k * CC + c]);
            } else if (i < 2 * HC * DIN + CC * CC + CC) {
                int c = i - (2 * HC * DIN + CC * CC);
                float s = b1[c];
                for (int k = 0; k < HC; ++k) s += gat_bias[k] * w1[k * CC + c];
                b1p[c] = s;
            } else {
                int q = i - (2 * HC * DIN + CC * CC + CC);
                int d = q / HH, h = q - d * HH;
                float s = 0.f;
                for (int c = 0; c < CC; ++c)
                    s += lin_edge_w[d * HC + h * CC + c] * att_edge[h * CC + c];
                we[q] = s * LOG2E;                     // pre-scale for exp2
            }
        }
    } else {
        int nb = gridDim.x - PREP_BLOCKS;
        for (int e = (blockIdx.x - PREP_BLOCKS) * 256 + threadIdx.x; e < E; e += nb * 256)
            atomicAdd(&icnt[ei[E + e]], 1);
    }
}

// ---------- xs = x @ lin_w (MFMA) -> packed xsp + a_src/a_dst (pre-scaled) ----------
__global__ __launch_bounds__(256) void k_xs(const float* __restrict__ x,
                                            const unsigned short* __restrict__ linwt,
                                            const float* __restrict__ att_src,
                                            const float* __restrict__ att_dst,
                                            uint2* __restrict__ xsp,
                                            float* __restrict__ a_src,
                                            float* __restrict__ a_dst, int N) {
    int lane = threadIdx.x & 63, w = threadIdx.x >> 6;
    int l15 = lane & 15, kg = (lane >> 4) * 8;
    int nb = blockIdx.x * 64;
    int arow = nb + w * 16 + l15;
    int arow_c = min(arow, N - 1);

    f32x4 acc[12];
    #pragma unroll
    for (int ct = 0; ct < 12; ++ct) acc[ct] = (f32x4){0.f, 0.f, 0.f, 0.f};

    #pragma unroll
    for (int k0 = 0; k0 < DIN; k0 += 32) {
        const float* ap = x + (size_t)arow_c * DIN + k0 + kg;
        float4 a0 = *(const float4*)ap;
        float4 a1 = *(const float4*)(ap + 4);
        bf16x8 af = pack8(a0, a1);
        #pragma unroll
        for (int ct = 0; ct < 12; ++ct) {
            bf16x8 bf = *(const bf16x8*)(linwt + (size_t)(ct * 16 + l15) * DIN + k0 + kg);
            acc[ct] = __builtin_amdgcn_mfma_f32_16x16x32_bf16(af, bf, acc[ct], 0, 0, 0);
        }
    }

    float asv[12], adv[12];
    #pragma unroll
    for (int ct = 0; ct < 12; ++ct) {
        int c = ct * 16 + l15;
        asv[ct] = att_src[c]; adv[ct] = att_dst[c];
    }

    int rbase = nb + w * 16 + (lane >> 4) * 4;
    #pragma unroll
    for (int j = 0; j < 4; ++j) {
        int r = rbase + j;
        bool ok = r < N;
        float ps0 = 0.f, ps1 = 0.f, ps2 = 0.f, pd0 = 0.f, pd1 = 0.f, pd2 = 0.f;
        #pragma unroll
        for (int ct = 0; ct < 12; ++ct) {
            float v = acc[ct][j];
            float s = v * asv[ct], d = v * adv[ct];
            if (ct < 4)      { ps0 += s; pd0 += d; }
            else if (ct < 8) { ps1 += s; pd1 += d; }
            else             { ps2 += s; pd2 += d; }
        }
        if (ok) {
            #pragma unroll
            for (int ct = 0; ct < 4; ++ct) {
                uint2 pk;
                pk.x = (unsigned)f2bf(acc[ct][j]) | ((unsigned)f2bf(acc[ct + 4][j]) << 16);
                pk.y = (unsigned)f2bf(acc[ct + 8][j]);
                xsp[(size_t)r * CC + ct * 16 + l15] = pk;
            }
        }
        #pragma unroll
        for (int o = 1; o < 16; o <<= 1) {
            ps0 += __shfl_xor(ps0, o, 64); pd0 += __shfl_xor(pd0, o, 64);
            ps1 += __shfl_xor(ps1, o, 64); pd1 += __shfl_xor(pd1, o, 64);
            ps2 += __shfl_xor(ps2, o, 64); pd2 += __shfl_xor(pd2, o, 64);
        }
        if (ok && l15 == 0) {
            a_src[r * HH + 0] = ps0 * LOG2E; a_src[r * HH + 1] = ps1 * LOG2E;
            a_src[r * HH + 2] = ps2 * LOG2E;
            a_dst[r * HH + 0] = pd0 * LOG2E; a_dst[r * HH + 1] = pd1 * LOG2E;
            a_dst[r * HH + 2] = pd2 * LOG2E;
        }
    }
}

// ---------- multi-block exclusive scan (3 kernels) ----------
__global__ __launch_bounds__(256) void k_scan1(const int* __restrict__ icnt,
                                               int* __restrict__ bsum, int N) {
    int i = blockIdx.x * 256 + threadIdx.x;
    int lane = threadIdx.x & 63, wid = threadIdx.x >> 6;
    int v = (i < N) ? icnt[i] : 0;
    #pragma unroll
    for (int o = 32; o; o >>= 1) v += __shfl_xor(v, o, 64);
    __shared__ int wt[4];
    if (lane == 0) wt[wid] = v;
    __syncthreads();
    if (threadIdx.x == 0) bsum[blockIdx.x] = wt[0] + wt[1] + wt[2] + wt[3];
}

__global__ __launch_bounds__(1024) void k_scan2(const int* __restrict__ bsum,
                                                int* __restrict__ boff, int nb) {
    __shared__ int s[1024];
    int t = threadIdx.x;
    int v = (t < nb) ? bsum[t] : 0;
    s[t] = v;
    __syncthreads();
    for (int d = 1; d < 1024; d <<= 1) {
        int u = (t >= d) ? s[t - d] : 0;
        __syncthreads();
        s[t] += u;
        __syncthreads();
    }
    if (t < nb) boff[t] = s[t] - v;   // exclusive
}

__global__ __launch_bounds__(256) void k_scan3(const int* __restrict__ icnt,
                                               const int* __restrict__ boff,
                                               int* __restrict__ off,
                                               int* __restrict__ cursor, int N) {
    int i = blockIdx.x * 256 + threadIdx.x;
    int lane = threadIdx.x & 63, wid = threadIdx.x >> 6;
    int v = (i < N) ? icnt[i] : 0;
    int incl = v;
    #pragma unroll
    for (int o = 1; o < 64; o <<= 1) {
        int u = __shfl_up(incl, o, 64);
        if (lane >= o) incl += u;
    }
    __shared__ int wt[4];
    if (lane == 63) wt[wid] = incl;
    __syncthreads();
    int wpre = 0;
    for (int w = 0; w < wid; ++w) wpre += wt[w];
    int excl = boff[blockIdx.x] + wpre + incl - v;
    if (i < N) {
        off[i] = excl;
        cursor[i] = excl;
        if (i == N - 1) off[N] = excl + v;
    }
}

// ---------- payload fill (CSR order), 16B/edge, NO float atomics ----------
// pk = { bf(lp0)|bf(lp1)<<16, bf(lp2)|bf(ae0)<<16, bf(ae1)|bf(ae2)<<16, src }
__global__ __launch_bounds__(256) void k_fill(const float* __restrict__ ea,
                                              const int* __restrict__ ei,
                                              const float* __restrict__ a_src,
                                              const float* __restrict__ we,
                                              int* __restrict__ cursor,
                                              uint4* __restrict__ payload, int E) {
    int e = blockIdx.x * blockDim.x + threadIdx.x;
    if (e >= E) return;
    int s = ei[e], d = ei[E + e];
    float attr[ED];
    #pragma unroll
    for (int j = 0; j < ED; ++j) attr[j] = ea[(size_t)e * ED + j];
    float aeh[HH], lp[HH];
    #pragma unroll
    for (int h = 0; h < HH; ++h) {
        float a = 0.f;
        #pragma unroll
        for (int j = 0; j < ED; ++j) a += attr[j] * we[j * HH + h];   // we pre-scaled
        aeh[h] = a;
        lp[h] = a_src[s * HH + h] + a;                                 // both scaled
    }
    int pos = atomicAdd(&cursor[d], 1);
    uint4 pk;
    pk.x = (unsigned)f2bf(lp[0])  | ((unsigned)f2bf(lp[1])  << 16);
    pk.y = (unsigned)f2bf(lp[2])  | ((unsigned)f2bf(aeh[0]) << 16);
    pk.z = (unsigned)f2bf(aeh[1]) | ((unsigned)f2bf(aeh[2]) << 16);
    pk.w = (unsigned)s;
    payload[pos] = pk;
}

// ---------- per-dst softmax + gather: two-phase, packed gather ----------
__global__ __launch_bounds__(256) void k_gat(const uint2* __restrict__ xsp,
                                             const float* __restrict__ a_src,
                                             const float* __restrict__ a_dst,
                                             const int* __restrict__ off,
                                             const uint4* __restrict__ payload,
                                             unsigned short* __restrict__ oaccb, int N) {
    __shared__ float4 wbuf[4][64];
    int lane = threadIdx.x & 63;
    int wid  = threadIdx.x >> 6;
    for (int n = blockIdx.x * 4 + wid; n < N; n += gridDim.x * 4) {
        int beg = off[n], end = off[n + 1];
        int deg = end - beg;
        float ad0 = a_dst[n * HH + 0], ad1 = a_dst[n * HH + 1], ad2 = a_dst[n * HH + 2];
        float pden0 = 0.f, pden1 = 0.f, pden2 = 0.f;     // per-lane partials
        float pae0 = 0.f, pae1 = 0.f, pae2 = 0.f;
        float a0A = 0.f, a1A = 0.f, a2A = 0.f;
        float a0B = 0.f, a1B = 0.f, a2B = 0.f;

        for (int c0 = 0; c0 < deg; c0 += 64) {
            int cn = min(deg - c0, 64);
            // --- phase A: lane = edge ---
            float w0 = 0.f, w1 = 0.f, w2 = 0.f;
            int src = 0;
            if (lane < cn) {
                uint4 p = payload[beg + c0 + lane];
                w0 = exp2f(leaky(bf_lo(p.x) + ad0));
                w1 = exp2f(leaky(bf_hi(p.x) + ad1));
                w2 = exp2f(leaky(bf_lo(p.y) + ad2));
                pae0 += bf_hi(p.y);
                pae1 += bf_lo(p.z);
                pae2 += bf_hi(p.z);
                pden0 += w0; pden1 += w1; pden2 += w2;
                src = (int)p.w;
            }
            wbuf[wid][lane] = make_float4(w0, w1, w2, __int_as_float(src));
            // --- phase B: lane = feature, one dwordx2 gather per edge ---
            int i = 0;
            for (; i + 2 <= cn; i += 2) {
                float4 ta = wbuf[wid][i];
                float4 tb = wbuf[wid][i + 1];
                unsigned ia = (unsigned)__float_as_int(ta.w) * CC + lane;
                unsigned ib = (unsigned)__float_as_int(tb.w) * CC + lane;
                uint2 va = xsp[ia];
                uint2 vb = xsp[ib];
                a0A += ta.x * bf_lo(va.x); a1A += ta.y * bf_hi(va.x); a2A += ta.z * bf_lo(va.y);
                a0B += tb.x * bf_lo(vb.x); a1B += tb.y * bf_hi(vb.x); a2B += tb.z * bf_lo(vb.y);
            }
            if (i < cn) {
                float4 ta = wbuf[wid][i];
                unsigned ia = (unsigned)__float_as_int(ta.w) * CC + lane;
                uint2 va = xsp[ia];
                a0A += ta.x * bf_lo(va.x); a1A += ta.y * bf_hi(va.x); a2A += ta.z * bf_lo(va.y);
            }
        }

        // reduce per-lane partials (den, ae)
        #pragma unroll
        for (int o = 32; o; o >>= 1) {
            pden0 += __shfl_xor(pden0, o, 64);
            pden1 += __shfl_xor(pden1, o, 64);
            pden2 += __shfl_xor(pden2, o, 64);
            pae0  += __shfl_xor(pae0, o, 64);
            pae1  += __shfl_xor(pae1, o, 64);
            pae2  += __shfl_xor(pae2, o, 64);
        }

        // self loop (edge attr = mean of incoming, 0 if deg==0); all pre-scaled
        float dc = fmaxf((float)deg, 1.0f);
        float inv_dc = 1.0f / dc;
        float sl0 = leaky(a_src[n * HH + 0] + ad0 + pae0 * inv_dc);
        float sl1 = leaky(a_src[n * HH + 1] + ad1 + pae1 * inv_dc);
        float sl2 = leaky(a_src[n * HH + 2] + ad2 + pae2 * inv_dc);
        float e0 = exp2f(sl0), e1 = exp2f(sl1), e2 = exp2f(sl2);
        uint2 vn = xsp[(unsigned)n * CC + lane];
        float den0 = pden0 + e0, den1 = pden1 + e1, den2 = pden2 + e2;
        float acc0 = a0A + a0B + e0 * bf_lo(vn.x);
        float acc1 = a1A + a1B + e1 * bf_hi(vn.x);
        float acc2 = a2A + a2B + e2 * bf_lo(vn.y);
        size_t nbse = (size_t)n * HC;
        oaccb[nbse + 0 * CC + lane] = f2bf(acc0 / den0);
        oaccb[nbse + 1 * CC + lane] = f2bf(acc1 / den1);
        oaccb[nbse + 2 * CC + lane] = f2bf(acc2 / den2);
    }
}

// ---------- fused MLP: GEMM1 -> LN1 -> GEMM2 -> LN2 (MFMA, in-reg LN) ----------
__global__ __launch_bounds__(256) void k_mlp(const unsigned short* __restrict__ oaccb,
                                             const unsigned short* __restrict__ w1t,
                                             const unsigned short* __restrict__ w2t,
                                             const float* __restrict__ b1p,
                                             const float* __restrict__ x,
                                             const float* __restrict__ g1,
                                             const float* __restrict__ be1,
                                             const float* __restrict__ b2,
                                             const float* __restrict__ g2,
                                             const float* __restrict__ be2,
                                             float* __restrict__ out, int N) {
    __shared__ unsigned short H1[64 * 72];   // [node-in-tile][feature] bf16, pad 72
    int lane = threadIdx.x & 63, w = threadIdx.x >> 6;
    int l15 = lane & 15, kg = (lane >> 4) * 8;
    int nb = blockIdx.x * 64;
    int arow = nb + w * 16 + l15;
    int arow_c = min(arow, N - 1);

    float c_b1[4], c_g1[4], c_be1[4], c_b2[4], c_g2[4], c_be2[4];
    #pragma unroll
    for (int ct = 0; ct < 4; ++ct) {
        int c = ct * 16 + l15;
        c_b1[ct] = b1p[c]; c_g1[ct] = g1[c]; c_be1[ct] = be1[c];
        c_b2[ct] = b2[c];  c_g2[ct] = g2[c]; c_be2[ct] = be2[c];
    }

    // GEMM1: [64 x 192] @ [192 x 64], A read directly as bf16
    f32x4 acc[4];
    #pragma unroll
    for (int ct = 0; ct < 4; ++ct) acc[ct] = (f32x4){0.f, 0.f, 0.f, 0.f};
    #pragma unroll
    for (int k0 = 0; k0 < HC; k0 += 32) {
        bf16x8 af = *(const bf16x8*)(oaccb + (size_t)arow_c * HC + k0 + kg);
        #pragma unroll
        for (int ct = 0; ct < 4; ++ct) {
            bf16x8 bf = *(const bf16x8*)(w1t + (size_t)(ct * 16 + l15) * HC + k0 + kg);
            acc[ct] = __builtin_amdgcn_mfma_f32_16x16x32_bf16(af, bf, acc[ct], 0, 0, 0);
        }
    }

    // epilogue1: y = acc + b1' + x ; LN1 -> h1 (regs + LDS bf16)
    int rbase = nb + w * 16 + (lane >> 4) * 4;
    int rloc0 = w * 16 + (lane >> 4) * 4;
    float h1v[4][4];
    float y[4][4];
    #pragma unroll
    for (int j = 0; j < 4; ++j) {
        int r = min(rbase + j, N - 1);
        #pragma unroll
        for (int ct = 0; ct < 4; ++ct)
            y[ct][j] = acc[ct][j] + c_b1[ct] + x[(size_t)r * DIN + ct * 16 + l15];
    }
    #pragma unroll
    for (int j = 0; j < 4; ++j) {
        float s = y[0][j] + y[1][j] + y[2][j] + y[3][j];
        #pragma unroll
        for (int o = 1; o < 16; o <<= 1) s += __shfl_xor(s, o, 64);
        float m = s * (1.0f / CC);
        float vs = 0.f;
        #pragma unroll
        for (int ct = 0; ct < 4; ++ct) { float d = y[ct][j] - m; vs += d * d; }
        #pragma unroll
        for (int o = 1; o < 16; o <<= 1) vs += __shfl_xor(vs, o, 64);
        float inv = rsqrtf(vs * (1.0f / CC) + LN_EPS);
        #pragma unroll
        for (int ct = 0; ct < 4; ++ct) {
            float h = (y[ct][j] - m) * inv * c_g1[ct] + c_be1[ct];
            h1v[ct][j] = h;
            H1[(rloc0 + j) * 72 + ct * 16 + l15] = f2bf(h);
        }
    }
    __syncthreads();

    // GEMM2: [64 x 64] @ [64 x 64]
    f32x4 acc2[4];
    #pragma unroll
    for (int ct = 0; ct < 4; ++ct) acc2[ct] = (f32x4){0.f, 0.f, 0.f, 0.f};
    #pragma unroll
    for (int k0 = 0; k0 < CC; k0 += 32) {
        bf16x8 af = *(const bf16x8*)&H1[(w * 16 + l15) * 72 + k0 + kg];
        #pragma unroll
        for (int ct = 0; ct < 4; ++ct) {
            bf16x8 bf = *(const bf16x8*)(w2t + (size_t)(ct * 16 + l15) * CC + k0 + kg);
            acc2[ct] = __builtin_amdgcn_mfma_f32_16x16x32_bf16(af, bf, acc2[ct], 0, 0, 0);
        }
    }

    // epilogue2: z = acc2 + b2 + h1 ; LN2 -> out
    #pragma unroll
    for (int j = 0; j < 4; ++j) {
        float z0 = acc2[0][j] + c_b2[0] + h1v[0][j];
        float z1 = acc2[1][j] + c_b2[1] + h1v[1][j];
        float z2 = acc2[2][j] + c_b2[2] + h1v[2][j];
        float z3 = acc2[3][j] + c_b2[3] + h1v[3][j];
        float s = z0 + z1 + z2 + z3;
        #pragma unroll
        for (int o = 1; o < 16; o <<= 1) s += __shfl_xor(s, o, 64);
        float m = s * (1.0f / CC);
        float d0 = z0 - m, d1 = z1 - m, d2 = z2 - m, d3 = z3 - m;
        float vs = d0 * d0 + d1 * d1 + d2 * d2 + d3 * d3;
        #pragma unroll
        for (int o = 1; o < 16; o <<= 1) vs += __shfl_xor(vs, o, 64);
        float inv = rsqrtf(vs * (1.0f / CC) + LN_EPS);
        int r = rbase + j;
        if (r < N) {
            out[(size_t)r * CC + 0 * 16 + l15] = d0 * inv * c_g2[0] + c_be2[0];
            out[(size_t)r * CC + 1 * 16 + l15] = d1 * inv * c_g2[1] + c_be2[1];
            out[(size_t)r * CC + 2 * 16 + l15] = d2 * inv * c_g2[2] + c_be2[2];
            out[(size_t)r * CC + 3 * 16 + l15] = d3 * inv * c_g2[3] + c_be2[3];
        }
    }
}

extern "C" void kernel_launch(void* const* d_in, const int* in_sizes, int n_in,
                              void* d_out, int out_size, void* d_ws, size_t ws_size,
                              hipStream_t stream) {
    const float* x          = (const float*)d_in[0];
    const float* edge_attr  = (const float*)d_in[1];
    const float* lin_w      = (const float*)d_in[2];
    const float* att_src    = (const float*)d_in[3];
    const float* att_dst    = (const float*)d_in[4];
    const float* lin_edge_w = (const float*)d_in[5];
    const float* att_edge   = (const float*)d_in[6];
    const float* gat_bias   = (const float*)d_in[7];
    const float* w1         = (const float*)d_in[8];
    const float* b1         = (const float*)d_in[9];
    const float* ln1_g      = (const float*)d_in[10];
    const float* ln1_b      = (const float*)d_in[11];
    const float* w2         = (const float*)d_in[12];
    const float* b2         = (const float*)d_in[13];
    const float* ln2_g      = (const float*)d_in[14];
    const float* ln2_b      = (const float*)d_in[15];
    const int*   ei         = (const int*)d_in[16];
    float* out = (float*)d_out;

    const int N = in_sizes[0] / DIN;
    const int E = in_sizes[1] / ED;
    const int nb_scan = (N + 255) / 256;

    char* ws = (char*)d_ws;
    size_t off_b = 0;
    auto alloc = [&](size_t bytes) {
        size_t o = off_b;
        off_b = (off_b + bytes + 255) & ~(size_t)255;
        return o;
    };
    // zeroed region first (single memset)
    int* icnt = (int*)(ws + alloc((size_t)N * 4));
    size_t zero_bytes = off_b;
    // fully-overwritten region
    uint2* xsp            = (uint2*)(ws + alloc((size_t)N * CC * 8));
    unsigned short* oaccb = (unsigned short*)(ws + alloc((size_t)N * HC * 2));
    float*  a_srcb  = (float*)(ws + alloc((size_t)N * HH * 4));
    float*  a_dstb  = (float*)(ws + alloc((size_t)N * HH * 4));
    int*    offb    = (int*)(ws + alloc((size_t)(N + 1) * 4));
    int*    cursor  = (int*)(ws + alloc((size_t)N * 4));
    int*    bsum    = (int*)(ws + alloc((size_t)nb_scan * 4));
    int*    boff    = (int*)(ws + alloc((size_t)nb_scan * 4));
    uint4*  payload = (uint4*)(ws + alloc((size_t)E * 16));
    unsigned short* linwt = (unsigned short*)(ws + alloc((size_t)HC * DIN * 2));
    unsigned short* w1t   = (unsigned short*)(ws + alloc((size_t)DIN * HC * 2));
    unsigned short* w2t   = (unsigned short*)(ws + alloc((size_t)CC * CC * 2));
    float* b1p = (float*)(ws + alloc((size_t)CC * 4));
    float* we  = (float*)(ws + alloc((size_t)ED * HH * 4));
    (void)ws_size; (void)n_in; (void)out_size;

    hipMemsetAsync(d_ws, 0, zero_bytes, stream);

    k_prep_cnt<<<PREP_BLOCKS + (E + 255) / 256, 256, 0, stream>>>(
        lin_w, w1, w2, b1, gat_bias, lin_edge_w, att_edge,
        linwt, w1t, w2t, b1p, we, ei, icnt, E);
    k_xs<<<(N + 63) / 64, 256, 0, stream>>>(x, linwt, att_src, att_dst, xsp, a_srcb, a_dstb, N);
    k_scan1<<<nb_scan, 256, 0, stream>>>(icnt, bsum, N);
    k_scan2<<<1, 1024, 0, stream>>>(bsum, boff, nb_scan);
    k_scan3<<<nb_scan, 256, 0, stream>>>(icnt, boff, offb, cursor, N);
    k_fill<<<(E + 255) / 256, 256, 0, stream>>>(edge_attr, ei, a_srcb, we, cursor,
                                                payload, E);
    k_gat<<<(N + 3) / 4, 256, 0, stream>>>(xsp, a_srcb, a_dstb, offb, payload, oaccb, N);
    k_mlp<<<(N + 63) / 64, 256, 0, stream>>>(oaccb, w1t, w2t, b1p, x,
                                             ln1_g, ln1_b, b2, ln2_g, ln2_b, out, N);
}